// Round 4
// baseline (783.414 us; speedup 1.0000x reference)
//
#include <hip/hip_runtime.h>
#include <math.h>

static inline int div_up(long long a, long long b) { return (int)((a + b - 1) / b); }

#define BSH 4                 // 16 nodes per bucket
#define BKT (1 << BSH)

// ---------------- CSR build ----------------

__global__ void k_zero_i32(int* __restrict__ p, int n) {
    int i = blockIdx.x * blockDim.x + threadIdx.x;
    if (i < n) p[i] = 0;
}

__global__ void k_cnt(const int* __restrict__ dst, int* __restrict__ cnt, int E) {
    int i = blockIdx.x * blockDim.x + threadIdx.x;
    int stride = gridDim.x * blockDim.x;
    for (; i < E; i += stride) atomicAdd(&cnt[dst[i]], 1);
}

// Single-workgroup exclusive scan. Also emits cur (= rp copy, the node cursor)
// and dis[i] = rsqrt(cnt[i] + 1) so no separate passes are needed.
__global__ void k_scan_excl(const int* __restrict__ cnt, int* __restrict__ rp,
                            int* __restrict__ cur, float* __restrict__ dis, int N) {
    __shared__ int wsum[16];
    __shared__ int s_carry;
    const int tid = threadIdx.x;
    const int lane = tid & 63, wid = tid >> 6;
    if (tid == 0) s_carry = 0;
    __syncthreads();
    for (int base = 0; base < N; base += 1024 * 8) {
        int i0 = base + tid * 8;
        int v[8];
        int t = 0;
#pragma unroll
        for (int j = 0; j < 8; ++j) {
            int idx = i0 + j;
            v[j] = (idx < N) ? cnt[idx] : 0;
            t += v[j];
        }
        int x = t;  // inclusive wave scan of per-thread totals
        for (int off = 1; off < 64; off <<= 1) {
            int y = __shfl_up(x, off);
            if (lane >= off) x += y;
        }
        if (lane == 63) wsum[wid] = x;
        __syncthreads();
        if (tid < 16) {
            int s = wsum[tid];
            for (int off = 1; off < 16; off <<= 1) {
                int y = __shfl_up(s, off);
                if (tid >= off) s += y;
            }
            wsum[tid] = s;
        }
        __syncthreads();
        int carry = s_carry;
        int woff = (wid > 0) ? wsum[wid - 1] : 0;
        int run = carry + woff + (x - t);
#pragma unroll
        for (int j = 0; j < 8; ++j) {
            int idx = i0 + j;
            if (idx < N) {
                rp[idx] = run;
                cur[idx] = run;
                dis[idx] = rsqrtf((float)v[j] + 1.0f);
            }
            run += v[j];
        }
        __syncthreads();
        if (tid == 0) s_carry = carry + wsum[15];
        __syncthreads();
    }
    if (tid == 0) rp[N] = s_carry;
}

// bcur[b] = rp[b * BKT]  (bucket b covers nodes [b*BKT, (b+1)*BKT))
__global__ void k_binit(const int* __restrict__ rp, int* __restrict__ bcur, int NB) {
    int b = blockIdx.x * blockDim.x + threadIdx.x;
    if (b < NB) bcur[b] = rp[b << BSH];
}

// Phase B: append (src,dst) pairs into bucket-contiguous regions.
__global__ void k_bucket(const int* __restrict__ src, const int* __restrict__ dst,
                         int* __restrict__ bcur, uint2* __restrict__ pairs, int E) {
    int i = blockIdx.x * blockDim.x + threadIdx.x;
    if (i >= E) return;
    int d = dst[i];
    int p = atomicAdd(&bcur[d >> BSH], 1);
    pairs[p] = make_uint2((unsigned)src[i], (unsigned)d);
}

// Phase C: place src ids at their exact CSR slots (reads sequential, writes
// land within the ~1KB bucket span of the temporally-neighboring waves).
__global__ void k_place(const uint2* __restrict__ pairs, int* __restrict__ cur,
                        int* __restrict__ csrc, int E) {
    int i = blockIdx.x * blockDim.x + threadIdx.x;
    if (i >= E) return;
    uint2 pr = pairs[i];
    int pos = atomicAdd(&cur[pr.y], 1);
    csrc[pos] = (int)pr.x;
}

// ---------------- propagation: h_out = A_hat_norm @ h_in (gather form) ----------------
// TPE = F/4 lanes per node; each lane owns one float4 column chunk.

template<int F>
__global__ void k_prop_gather(const int* __restrict__ rp, const int* __restrict__ csrc,
                              const float* __restrict__ dis,
                              const float* __restrict__ hin, float* __restrict__ hout, int N) {
    constexpr int TPE = F / 4;
    int t = blockIdx.x * blockDim.x + threadIdx.x;
    int n = t / TPE;
    if (n >= N) return;
    int l = t % TPE;
    float dn = dis[n];
    float4 acc = *reinterpret_cast<const float4*>(hin + (size_t)n * F + 4 * l);
    float wn = dn * dn;
    acc.x *= wn; acc.y *= wn; acc.z *= wn; acc.w *= wn;
    int e = rp[n], end = rp[n + 1];
    for (; e + 3 < end; e += 4) {
        int s0 = csrc[e], s1 = csrc[e + 1], s2 = csrc[e + 2], s3 = csrc[e + 3];
        float w0 = dis[s0] * dn, w1 = dis[s1] * dn;
        float w2 = dis[s2] * dn, w3 = dis[s3] * dn;
        float4 v0 = *reinterpret_cast<const float4*>(hin + (size_t)s0 * F + 4 * l);
        float4 v1 = *reinterpret_cast<const float4*>(hin + (size_t)s1 * F + 4 * l);
        float4 v2 = *reinterpret_cast<const float4*>(hin + (size_t)s2 * F + 4 * l);
        float4 v3 = *reinterpret_cast<const float4*>(hin + (size_t)s3 * F + 4 * l);
        acc.x += w0 * v0.x + w1 * v1.x + w2 * v2.x + w3 * v3.x;
        acc.y += w0 * v0.y + w1 * v1.y + w2 * v2.y + w3 * v3.y;
        acc.z += w0 * v0.z + w1 * v1.z + w2 * v2.z + w3 * v3.z;
        acc.w += w0 * v0.w + w1 * v1.w + w2 * v2.w + w3 * v3.w;
    }
    for (; e < end; ++e) {
        int s0 = csrc[e];
        float w0 = dis[s0] * dn;
        float4 v0 = *reinterpret_cast<const float4*>(hin + (size_t)s0 * F + 4 * l);
        acc.x += w0 * v0.x; acc.y += w0 * v0.y; acc.z += w0 * v0.z; acc.w += w0 * v0.w;
    }
    *reinterpret_cast<float4*>(hout + (size_t)n * F + 4 * l) = acc;
}

// ---------------- dense layers ----------------

// Y0[n,h] = X[n,:128] @ W1[:,h]   (bias/relu moved after propagation)
__global__ void k_gemm_128_64(const float* __restrict__ X, const float* __restrict__ W,
                              float* __restrict__ Y, int N) {
    __shared__ float sx[4][128];
    int node0 = blockIdx.x * 4;
    int tid = threadIdx.x;
    for (int i = tid; i < 4 * 128; i += 256) {
        int n = node0 + i / 128;
        sx[i / 128][i % 128] = (n < N) ? X[(size_t)n * 128 + (i % 128)] : 0.0f;
    }
    __syncthreads();
    int ln = tid >> 6;
    int h  = tid & 63;
    int n = node0 + ln;
    if (n >= N) return;
    float acc = 0.0f;
#pragma unroll 8
    for (int k = 0; k < 128; ++k) acc += sx[ln][k] * W[k * 64 + h];
    Y[(size_t)n * 64 + h] = acc;
}

// T[n,c] = sum_k relu(H[n,k] + b1[k]) * W2[k,c]   (N x 64 -> N x 40, stride 40)
__global__ void k_relu_gemm_64_40(const float* __restrict__ H, const float* __restrict__ b1,
                                  const float* __restrict__ W2, float* __restrict__ T,
                                  int NC) {
    int t = blockIdx.x * blockDim.x + threadIdx.x;
    if (t >= NC) return;
    int n = t / 40;
    int c = t % 40;
    const float* hr = H + (size_t)n * 64;
    float acc = 0.0f;
#pragma unroll 8
    for (int k = 0; k < 64; ++k) acc += fmaxf(hr[k] + b1[k], 0.0f) * W2[k * 40 + c];
    T[t] = acc;
}

// out[n,c] = log_softmax(T[n,:40] + b2)   one wave per node, lanes >= 40 padded
__global__ void k_bias_lsm(const float* __restrict__ T, const float* __restrict__ b2,
                           float* __restrict__ Y, int N) {
    int gid = blockIdx.x * blockDim.x + threadIdx.x;
    int node = gid >> 6;
    int lane = threadIdx.x & 63;
    if (node >= N) return;
    float v = (lane < 40) ? T[(size_t)node * 40 + lane] + b2[lane] : -INFINITY;
    float m = v;
    for (int off = 32; off >= 1; off >>= 1) m = fmaxf(m, __shfl_xor(m, off));
    float ev = (lane < 40) ? expf(v - m) : 0.0f;
    float s = ev;
    for (int off = 32; off >= 1; off >>= 1) s += __shfl_xor(s, off);
    if (lane < 40) Y[(size_t)node * 40 + lane] = v - m - logf(s);
}

// ---------------- launch ----------------

extern "C" void kernel_launch(void* const* d_in, const int* in_sizes, int n_in,
                              void* d_out, int out_size, void* d_ws, size_t ws_size,
                              hipStream_t stream) {
    const float* x  = (const float*)d_in[0];
    const int*   ei = (const int*)d_in[1];
    const float* W1 = (const float*)d_in[2];
    const float* b1 = (const float*)d_in[3];
    const float* W2 = (const float*)d_in[4];
    const float* b2 = (const float*)d_in[5];
    float* out = (float*)d_out;

    const int H = in_sizes[3];            // 64
    const int F = in_sizes[2] / H;        // 128
    const int N = in_sizes[0] / F;        // 100000
    const int E = in_sizes[1] / 2;        // 1600000
    (void)ws_size; (void)n_in; (void)out_size;

    const int* src = ei;
    const int* dst = ei + E;
    const int NB = div_up(N, BKT);

    // workspace layout (4-byte elems)
    const int Npad = (N + 256) & ~255;          // covers N+1
    float* dis  = (float*)d_ws;                 // N
    int*   cnt  = (int*)(dis + Npad);           // N
    int*   rp   = cnt + Npad;                   // N+1
    int*   cur  = rp + Npad;                    // N   (node cursor for k_place)
    int*   bcur = cur + Npad;                   // NB  (bucket cursor)
    int*   csrc = bcur + ((NB + 255) & ~255);   // E
    float* bufA = (float*)(csrc + ((E + 255) & ~255));   // N*64
    float* bufB = bufA + (size_t)N * 64;                 // N*64
    uint2* pairs = (uint2*)bufB;                // 2E ints, aliases bufB (dead until prop 1)

    const int B = 256;

    // ---- CSR build ----
    k_zero_i32<<<div_up(N, B), B, 0, stream>>>(cnt, N);
    k_cnt<<<div_up(E, B * 8), B, 0, stream>>>(dst, cnt, E);
    k_scan_excl<<<1, 1024, 0, stream>>>(cnt, rp, cur, dis, N);
    k_binit<<<div_up(NB, B), B, 0, stream>>>(rp, bcur, NB);
    k_bucket<<<div_up(E, B), B, 0, stream>>>(src, dst, bcur, pairs, E);
    k_place<<<div_up(E, B), B, 0, stream>>>(pairs, cur, csrc, E);

    // ---- layer 1 (commuted): Y0 = X @ W1, then 2 props at F=64 ----
    k_gemm_128_64<<<div_up(N, 4), 256, 0, stream>>>(x, W1, bufA, N);
    k_prop_gather<64><<<div_up((long long)N * 16, B), B, 0, stream>>>(rp, csrc, dis, bufA, bufB, N);
    k_prop_gather<64><<<div_up((long long)N * 16, B), B, 0, stream>>>(rp, csrc, dis, bufB, bufA, N);

    // ---- layer 2 (commuted): T = relu(h + b1) @ W2, then 2 props at F=40 ----
    k_relu_gemm_64_40<<<div_up((long long)N * 40, B), B, 0, stream>>>(bufA, b1, W2, bufB, N * 40);
    k_prop_gather<40><<<div_up((long long)N * 10, B), B, 0, stream>>>(rp, csrc, dis, bufB, bufA, N);
    k_prop_gather<40><<<div_up((long long)N * 10, B), B, 0, stream>>>(rp, csrc, dis, bufA, bufB, N);

    // ---- epilogue: out = log_softmax(T + b2) ----
    k_bias_lsm<<<div_up((long long)N * 64, 256), 256, 0, stream>>>(bufB, b2, out, N);
}

// Round 5
// 616.419 us; speedup vs baseline: 1.2709x; 1.2709x over previous
//
#include <hip/hip_runtime.h>
#include <math.h>

static inline int div_up(long long a, long long b) { return (int)((a + b - 1) / b); }

#define BSH 4                 // 16 nodes per bucket
#define BKT (1 << BSH)
#define SCH 2048              // scan chunk per block

// ---------------- CSR build ----------------

__global__ void k_zero_i32(int* __restrict__ p, int n) {
    int i = blockIdx.x * blockDim.x + threadIdx.x;
    if (i < n) p[i] = 0;
}

__global__ void k_cnt(const int* __restrict__ dst, int* __restrict__ cnt, int E) {
    int i = blockIdx.x * blockDim.x + threadIdx.x;
    int stride = gridDim.x * blockDim.x;
    for (; i < E; i += stride) atomicAdd(&cnt[dst[i]], 1);
}

// Phase 1: per-block sums of SCH-element chunks.
__global__ void k_scan_part(const int* __restrict__ cnt, int* __restrict__ bsum, int N) {
    __shared__ int ws[4];
    int base = blockIdx.x * SCH + threadIdx.x * 8;
    int t = 0;
#pragma unroll
    for (int j = 0; j < 8; ++j) {
        int idx = base + j;
        if (idx < N) t += cnt[idx];
    }
    for (int off = 32; off >= 1; off >>= 1) t += __shfl_xor(t, off);
    int lane = threadIdx.x & 63, wid = threadIdx.x >> 6;
    if (lane == 0) ws[wid] = t;
    __syncthreads();
    if (threadIdx.x == 0) bsum[blockIdx.x] = ws[0] + ws[1] + ws[2] + ws[3];
}

// Phase 2: exclusive scan of block sums (NB <= 1024) + grand total -> rpN.
__global__ void k_scan_bsums(int* __restrict__ bsum, int* __restrict__ rpN, int NB) {
    __shared__ int wsum[16];
    int tid = threadIdx.x;
    int v = (tid < NB) ? bsum[tid] : 0;
    int lane = tid & 63, wid = tid >> 6;
    int x = v;
    for (int off = 1; off < 64; off <<= 1) {
        int y = __shfl_up(x, off);
        if (lane >= off) x += y;
    }
    if (lane == 63) wsum[wid] = x;
    __syncthreads();
    if (tid < 16) {
        int s = wsum[tid];
        for (int off = 1; off < 16; off <<= 1) {
            int y = __shfl_up(s, off);
            if (tid >= off) s += y;
        }
        wsum[tid] = s;
    }
    __syncthreads();
    int woff = (wid > 0) ? wsum[wid - 1] : 0;
    int excl = woff + x - v;
    if (tid < NB) bsum[tid] = excl;
    if (tid == NB - 1) rpN[0] = excl + v;
}

// Phase 3: local exclusive scan + block offset; emits rp, cur, dis.
__global__ void k_scan_apply(const int* __restrict__ cnt, const int* __restrict__ bsum,
                             int* __restrict__ rp, int* __restrict__ cur,
                             float* __restrict__ dis, int N) {
    __shared__ int wsum[4];
    int tid = threadIdx.x;
    int base = blockIdx.x * SCH + tid * 8;
    int v[8];
    int t = 0;
#pragma unroll
    for (int j = 0; j < 8; ++j) {
        int idx = base + j;
        v[j] = (idx < N) ? cnt[idx] : 0;
        t += v[j];
    }
    int lane = tid & 63, wid = tid >> 6;
    int x = t;
    for (int off = 1; off < 64; off <<= 1) {
        int y = __shfl_up(x, off);
        if (lane >= off) x += y;
    }
    if (lane == 63) wsum[wid] = x;
    __syncthreads();
    int woff = 0;
    for (int w = 0; w < wid; ++w) woff += wsum[w];
    int run = bsum[blockIdx.x] + woff + (x - t);
#pragma unroll
    for (int j = 0; j < 8; ++j) {
        int idx = base + j;
        if (idx < N) {
            rp[idx] = run;
            cur[idx] = run;
            dis[idx] = rsqrtf((float)v[j] + 1.0f);
        }
        run += v[j];
    }
}

// bcur[b] = rp[b * BKT]
__global__ void k_binit(const int* __restrict__ rp, int* __restrict__ bcur, int NB) {
    int b = blockIdx.x * blockDim.x + threadIdx.x;
    if (b < NB) bcur[b] = rp[b << BSH];
}

// Phase B: append (src,dst) pairs into bucket-contiguous regions.
__global__ void k_bucket(const int* __restrict__ src, const int* __restrict__ dst,
                         int* __restrict__ bcur, uint2* __restrict__ pairs, int E) {
    int i = blockIdx.x * blockDim.x + threadIdx.x;
    if (i >= E) return;
    int d = dst[i];
    int p = atomicAdd(&bcur[d >> BSH], 1);
    pairs[p] = make_uint2((unsigned)src[i], (unsigned)d);
}

// Phase C: place src ids at exact CSR slots (reads sequential, writes bucket-local).
__global__ void k_place(const uint2* __restrict__ pairs, int* __restrict__ cur,
                        int* __restrict__ csrc, int E) {
    int i = blockIdx.x * blockDim.x + threadIdx.x;
    if (i >= E) return;
    uint2 pr = pairs[i];
    int pos = atomicAdd(&cur[pr.y], 1);
    csrc[pos] = (int)pr.x;
}

// ---------------- propagation: h_out = A_hat_norm @ h_in (gather form) ----------------

template<int F>
__global__ void k_prop_gather(const int* __restrict__ rp, const int* __restrict__ csrc,
                              const float* __restrict__ dis,
                              const float* __restrict__ hin, float* __restrict__ hout, int N) {
    constexpr int TPE = F / 4;
    int t = blockIdx.x * blockDim.x + threadIdx.x;
    int n = t / TPE;
    if (n >= N) return;
    int l = t % TPE;
    float dn = dis[n];
    float4 acc = *reinterpret_cast<const float4*>(hin + (size_t)n * F + 4 * l);
    float wn = dn * dn;
    acc.x *= wn; acc.y *= wn; acc.z *= wn; acc.w *= wn;
    int e = rp[n], end = rp[n + 1];
    for (; e + 3 < end; e += 4) {
        int s0 = csrc[e], s1 = csrc[e + 1], s2 = csrc[e + 2], s3 = csrc[e + 3];
        float w0 = dis[s0] * dn, w1 = dis[s1] * dn;
        float w2 = dis[s2] * dn, w3 = dis[s3] * dn;
        float4 v0 = *reinterpret_cast<const float4*>(hin + (size_t)s0 * F + 4 * l);
        float4 v1 = *reinterpret_cast<const float4*>(hin + (size_t)s1 * F + 4 * l);
        float4 v2 = *reinterpret_cast<const float4*>(hin + (size_t)s2 * F + 4 * l);
        float4 v3 = *reinterpret_cast<const float4*>(hin + (size_t)s3 * F + 4 * l);
        acc.x += w0 * v0.x + w1 * v1.x + w2 * v2.x + w3 * v3.x;
        acc.y += w0 * v0.y + w1 * v1.y + w2 * v2.y + w3 * v3.y;
        acc.z += w0 * v0.z + w1 * v1.z + w2 * v2.z + w3 * v3.z;
        acc.w += w0 * v0.w + w1 * v1.w + w2 * v2.w + w3 * v3.w;
    }
    for (; e < end; ++e) {
        int s0 = csrc[e];
        float w0 = dis[s0] * dn;
        float4 v0 = *reinterpret_cast<const float4*>(hin + (size_t)s0 * F + 4 * l);
        acc.x += w0 * v0.x; acc.y += w0 * v0.y; acc.z += w0 * v0.z; acc.w += w0 * v0.w;
    }
    *reinterpret_cast<float4*>(hout + (size_t)n * F + 4 * l) = acc;
}

// ---------------- dense layers ----------------

__global__ void k_gemm_128_64(const float* __restrict__ X, const float* __restrict__ W,
                              float* __restrict__ Y, int N) {
    __shared__ float sx[4][128];
    int node0 = blockIdx.x * 4;
    int tid = threadIdx.x;
    for (int i = tid; i < 4 * 128; i += 256) {
        int n = node0 + i / 128;
        sx[i / 128][i % 128] = (n < N) ? X[(size_t)n * 128 + (i % 128)] : 0.0f;
    }
    __syncthreads();
    int ln = tid >> 6;
    int h  = tid & 63;
    int n = node0 + ln;
    if (n >= N) return;
    float acc = 0.0f;
#pragma unroll 8
    for (int k = 0; k < 128; ++k) acc += sx[ln][k] * W[k * 64 + h];
    Y[(size_t)n * 64 + h] = acc;
}

__global__ void k_relu_gemm_64_40(const float* __restrict__ H, const float* __restrict__ b1,
                                  const float* __restrict__ W2, float* __restrict__ T,
                                  int NC) {
    int t = blockIdx.x * blockDim.x + threadIdx.x;
    if (t >= NC) return;
    int n = t / 40;
    int c = t % 40;
    const float* hr = H + (size_t)n * 64;
    float acc = 0.0f;
#pragma unroll 8
    for (int k = 0; k < 64; ++k) acc += fmaxf(hr[k] + b1[k], 0.0f) * W2[k * 40 + c];
    T[t] = acc;
}

__global__ void k_bias_lsm(const float* __restrict__ T, const float* __restrict__ b2,
                           float* __restrict__ Y, int N) {
    int gid = blockIdx.x * blockDim.x + threadIdx.x;
    int node = gid >> 6;
    int lane = threadIdx.x & 63;
    if (node >= N) return;
    float v = (lane < 40) ? T[(size_t)node * 40 + lane] + b2[lane] : -INFINITY;
    float m = v;
    for (int off = 32; off >= 1; off >>= 1) m = fmaxf(m, __shfl_xor(m, off));
    float ev = (lane < 40) ? expf(v - m) : 0.0f;
    float s = ev;
    for (int off = 32; off >= 1; off >>= 1) s += __shfl_xor(s, off);
    if (lane < 40) Y[(size_t)node * 40 + lane] = v - m - logf(s);
}

// ---------------- launch ----------------

extern "C" void kernel_launch(void* const* d_in, const int* in_sizes, int n_in,
                              void* d_out, int out_size, void* d_ws, size_t ws_size,
                              hipStream_t stream) {
    const float* x  = (const float*)d_in[0];
    const int*   ei = (const int*)d_in[1];
    const float* W1 = (const float*)d_in[2];
    const float* b1 = (const float*)d_in[3];
    const float* W2 = (const float*)d_in[4];
    const float* b2 = (const float*)d_in[5];
    float* out = (float*)d_out;

    const int H = in_sizes[3];            // 64
    const int F = in_sizes[2] / H;        // 128
    const int N = in_sizes[0] / F;        // 100000
    const int E = in_sizes[1] / 2;        // 1600000
    (void)ws_size; (void)n_in; (void)out_size;

    const int* src = ei;
    const int* dst = ei + E;
    const int NB = div_up(N, BKT);        // buckets
    const int NSB = div_up(N, SCH);       // scan blocks (49)

    // workspace layout (4-byte elems)
    const int Npad = (N + 256) & ~255;          // covers N+1
    float* dis  = (float*)d_ws;                 // N
    int*   cnt  = (int*)(dis + Npad);           // N
    int*   rp   = cnt + Npad;                   // N+1
    int*   cur  = rp + Npad;                    // N
    int*   bcur = cur + Npad;                   // NB
    int*   bsum = bcur + ((NB + 255) & ~255);   // NSB
    int*   csrc = bsum + ((NSB + 255) & ~255);  // E
    float* bufA = (float*)(csrc + ((E + 255) & ~255));   // N*64
    float* bufB = bufA + (size_t)N * 64;                 // N*64
    uint2* pairs = (uint2*)bufB;                // 2E ints, aliases bufB (dead until prop 1)

    const int B = 256;

    // ---- CSR build ----
    k_zero_i32<<<div_up(N, B), B, 0, stream>>>(cnt, N);
    k_cnt<<<div_up(E, B * 8), B, 0, stream>>>(dst, cnt, E);
    k_scan_part<<<NSB, 256, 0, stream>>>(cnt, bsum, N);
    k_scan_bsums<<<1, 1024, 0, stream>>>(bsum, rp + N, NSB);
    k_scan_apply<<<NSB, 256, 0, stream>>>(cnt, bsum, rp, cur, dis, N);
    k_binit<<<div_up(NB, B), B, 0, stream>>>(rp, bcur, NB);
    k_bucket<<<div_up(E, B), B, 0, stream>>>(src, dst, bcur, pairs, E);
    k_place<<<div_up(E, B), B, 0, stream>>>(pairs, cur, csrc, E);

    // ---- layer 1 (commuted): Y0 = X @ W1, then 2 props at F=64 ----
    k_gemm_128_64<<<div_up(N, 4), 256, 0, stream>>>(x, W1, bufA, N);
    k_prop_gather<64><<<div_up((long long)N * 16, B), B, 0, stream>>>(rp, csrc, dis, bufA, bufB, N);
    k_prop_gather<64><<<div_up((long long)N * 16, B), B, 0, stream>>>(rp, csrc, dis, bufB, bufA, N);

    // ---- layer 2 (commuted): T = relu(h + b1) @ W2, then 2 props at F=40 ----
    k_relu_gemm_64_40<<<div_up((long long)N * 40, B), B, 0, stream>>>(bufA, b1, W2, bufB, N * 40);
    k_prop_gather<40><<<div_up((long long)N * 10, B), B, 0, stream>>>(rp, csrc, dis, bufB, bufA, N);
    k_prop_gather<40><<<div_up((long long)N * 10, B), B, 0, stream>>>(rp, csrc, dis, bufA, bufB, N);

    // ---- epilogue: out = log_softmax(T + b2) ----
    k_bias_lsm<<<div_up((long long)N * 64, 256), 256, 0, stream>>>(bufB, b2, out, N);
}

// Round 6
// 507.436 us; speedup vs baseline: 1.5439x; 1.2148x over previous
//
#include <hip/hip_runtime.h>
#include <math.h>

static inline int div_up(long long a, long long b) { return (int)((a + b - 1) / b); }

#define BSH 4                 // 16 nodes per bucket
#define BKT (1 << BSH)
#define SCH 2048              // scan chunk per block

// ---------------- CSR build ----------------

__global__ void k_zero_i32(int* __restrict__ p, int n) {
    int i = blockIdx.x * blockDim.x + threadIdx.x;
    if (i < n) p[i] = 0;
}

__global__ void k_cnt(const int* __restrict__ dst, int* __restrict__ cnt, int E) {
    int i = blockIdx.x * blockDim.x + threadIdx.x;
    int stride = gridDim.x * blockDim.x;
    for (; i < E; i += stride) atomicAdd(&cnt[dst[i]], 1);
}

// Phase 1: per-block sums of SCH-element chunks.
__global__ void k_scan_part(const int* __restrict__ cnt, int* __restrict__ bsum, int N) {
    __shared__ int ws[4];
    int base = blockIdx.x * SCH + threadIdx.x * 8;
    int t = 0;
#pragma unroll
    for (int j = 0; j < 8; ++j) {
        int idx = base + j;
        if (idx < N) t += cnt[idx];
    }
    for (int off = 32; off >= 1; off >>= 1) t += __shfl_xor(t, off);
    int lane = threadIdx.x & 63, wid = threadIdx.x >> 6;
    if (lane == 0) ws[wid] = t;
    __syncthreads();
    if (threadIdx.x == 0) bsum[blockIdx.x] = ws[0] + ws[1] + ws[2] + ws[3];
}

// Phase 2: exclusive scan of block sums (NB <= 1024) + grand total -> rpN.
__global__ void k_scan_bsums(int* __restrict__ bsum, int* __restrict__ rpN, int NB) {
    __shared__ int wsum[16];
    int tid = threadIdx.x;
    int v = (tid < NB) ? bsum[tid] : 0;
    int lane = tid & 63, wid = tid >> 6;
    int x = v;
    for (int off = 1; off < 64; off <<= 1) {
        int y = __shfl_up(x, off);
        if (lane >= off) x += y;
    }
    if (lane == 63) wsum[wid] = x;
    __syncthreads();
    if (tid < 16) {
        int s = wsum[tid];
        for (int off = 1; off < 16; off <<= 1) {
            int y = __shfl_up(s, off);
            if (tid >= off) s += y;
        }
        wsum[tid] = s;
    }
    __syncthreads();
    int woff = (wid > 0) ? wsum[wid - 1] : 0;
    int excl = woff + x - v;
    if (tid < NB) bsum[tid] = excl;
    if (tid == NB - 1) rpN[0] = excl + v;
}

// Phase 3: local exclusive scan + block offset; emits rp, cur, dis.
__global__ void k_scan_apply(const int* __restrict__ cnt, const int* __restrict__ bsum,
                             int* __restrict__ rp, int* __restrict__ cur,
                             float* __restrict__ dis, int N) {
    __shared__ int wsum[4];
    int tid = threadIdx.x;
    int base = blockIdx.x * SCH + tid * 8;
    int v[8];
    int t = 0;
#pragma unroll
    for (int j = 0; j < 8; ++j) {
        int idx = base + j;
        v[j] = (idx < N) ? cnt[idx] : 0;
        t += v[j];
    }
    int lane = tid & 63, wid = tid >> 6;
    int x = t;
    for (int off = 1; off < 64; off <<= 1) {
        int y = __shfl_up(x, off);
        if (lane >= off) x += y;
    }
    if (lane == 63) wsum[wid] = x;
    __syncthreads();
    int woff = 0;
    for (int w = 0; w < wid; ++w) woff += wsum[w];
    int run = bsum[blockIdx.x] + woff + (x - t);
#pragma unroll
    for (int j = 0; j < 8; ++j) {
        int idx = base + j;
        if (idx < N) {
            rp[idx] = run;
            cur[idx] = run;
            dis[idx] = rsqrtf((float)v[j] + 1.0f);
        }
        run += v[j];
    }
}

// bcur[b] = rp[b * BKT]
__global__ void k_binit(const int* __restrict__ rp, int* __restrict__ bcur, int NB) {
    int b = blockIdx.x * blockDim.x + threadIdx.x;
    if (b < NB) bcur[b] = rp[b << BSH];
}

// Phase B: append (src,dst) pairs into bucket-contiguous regions.
__global__ void k_bucket(const int* __restrict__ src, const int* __restrict__ dst,
                         int* __restrict__ bcur, uint2* __restrict__ pairs, int E) {
    int i = blockIdx.x * blockDim.x + threadIdx.x;
    if (i >= E) return;
    int d = dst[i];
    int p = atomicAdd(&bcur[d >> BSH], 1);
    pairs[p] = make_uint2((unsigned)src[i], (unsigned)d);
}

// Phase C: place src ids at exact CSR slots (reads sequential, writes bucket-local).
__global__ void k_place(const uint2* __restrict__ pairs, int* __restrict__ cur,
                        int* __restrict__ csrc, int E) {
    int i = blockIdx.x * blockDim.x + threadIdx.x;
    if (i >= E) return;
    uint2 pr = pairs[i];
    int pos = atomicAdd(&cur[pr.y], 1);
    csrc[pos] = (int)pr.x;
}

// ---------------- propagation: h_out = A_hat_norm @ h_in (gather form) ----------------

template<int F>
__global__ void k_prop_gather(const int* __restrict__ rp, const int* __restrict__ csrc,
                              const float* __restrict__ dis,
                              const float* __restrict__ hin, float* __restrict__ hout, int N) {
    constexpr int TPE = F / 4;
    int t = blockIdx.x * blockDim.x + threadIdx.x;
    int n = t / TPE;
    if (n >= N) return;
    int l = t % TPE;
    float dn = dis[n];
    float4 acc = *reinterpret_cast<const float4*>(hin + (size_t)n * F + 4 * l);
    float wn = dn * dn;
    acc.x *= wn; acc.y *= wn; acc.z *= wn; acc.w *= wn;
    int e = rp[n], end = rp[n + 1];
    for (; e + 3 < end; e += 4) {
        int s0 = csrc[e], s1 = csrc[e + 1], s2 = csrc[e + 2], s3 = csrc[e + 3];
        float w0 = dis[s0] * dn, w1 = dis[s1] * dn;
        float w2 = dis[s2] * dn, w3 = dis[s3] * dn;
        float4 v0 = *reinterpret_cast<const float4*>(hin + (size_t)s0 * F + 4 * l);
        float4 v1 = *reinterpret_cast<const float4*>(hin + (size_t)s1 * F + 4 * l);
        float4 v2 = *reinterpret_cast<const float4*>(hin + (size_t)s2 * F + 4 * l);
        float4 v3 = *reinterpret_cast<const float4*>(hin + (size_t)s3 * F + 4 * l);
        acc.x += w0 * v0.x + w1 * v1.x + w2 * v2.x + w3 * v3.x;
        acc.y += w0 * v0.y + w1 * v1.y + w2 * v2.y + w3 * v3.y;
        acc.z += w0 * v0.z + w1 * v1.z + w2 * v2.z + w3 * v3.z;
        acc.w += w0 * v0.w + w1 * v1.w + w2 * v2.w + w3 * v3.w;
    }
    for (; e < end; ++e) {
        int s0 = csrc[e];
        float w0 = dis[s0] * dn;
        float4 v0 = *reinterpret_cast<const float4*>(hin + (size_t)s0 * F + 4 * l);
        acc.x += w0 * v0.x; acc.y += w0 * v0.y; acc.z += w0 * v0.z; acc.w += w0 * v0.w;
    }
    *reinterpret_cast<float4*>(hout + (size_t)n * F + 4 * l) = acc;
}

// ---------------- dense layers (register-tiled) ----------------

#define FMA4(a, s, v) { (a).x += (s) * (v).x; (a).y += (s) * (v).y; \
                        (a).z += (s) * (v).z; (a).w += (s) * (v).w; }

// Y[n,h] = X[n,:128] @ W[:,h].  Tile: 64 nodes x 64 h, 4x4 per thread.
__global__ __launch_bounds__(256) void k_gemm1(const float* __restrict__ X,
                                               const float* __restrict__ W,
                                               float* __restrict__ Y, int N) {
    __shared__ float sx[64][132];
    __shared__ float sw[128][68];
    const int tid = threadIdx.x;
    const int n0 = blockIdx.x * 64;
    const bool full = (n0 + 64 <= N);
    // stage W1 (128x64)
#pragma unroll
    for (int j = 0; j < 8; ++j) {
        int idx = (tid + j * 256) * 4;
        int k = idx >> 6, h = idx & 63;
        *reinterpret_cast<float4*>(&sw[k][h]) = *reinterpret_cast<const float4*>(W + idx);
    }
    // stage X tile (64x128)
#pragma unroll
    for (int j = 0; j < 8; ++j) {
        int idx = (tid + j * 256) * 4;
        int n = idx >> 7, k = idx & 127;
        float4 v = make_float4(0.f, 0.f, 0.f, 0.f);
        if (full || n0 + n < N)
            v = *reinterpret_cast<const float4*>(X + (size_t)(n0 + n) * 128 + k);
        *reinterpret_cast<float4*>(&sx[n][k]) = v;
    }
    __syncthreads();
    const int lane = tid & 63, wid = tid >> 6;
    const int h0 = (lane & 15) * 4;
    const int nb = wid * 16 + (lane >> 4) * 4;
    float4 a0 = {0,0,0,0}, a1 = {0,0,0,0}, a2 = {0,0,0,0}, a3 = {0,0,0,0};
#pragma unroll 4
    for (int k0 = 0; k0 < 128; k0 += 4) {
        float4 x0 = *reinterpret_cast<float4*>(&sx[nb + 0][k0]);
        float4 x1 = *reinterpret_cast<float4*>(&sx[nb + 1][k0]);
        float4 x2 = *reinterpret_cast<float4*>(&sx[nb + 2][k0]);
        float4 x3 = *reinterpret_cast<float4*>(&sx[nb + 3][k0]);
        float4 w0 = *reinterpret_cast<float4*>(&sw[k0 + 0][h0]);
        float4 w1 = *reinterpret_cast<float4*>(&sw[k0 + 1][h0]);
        float4 w2 = *reinterpret_cast<float4*>(&sw[k0 + 2][h0]);
        float4 w3 = *reinterpret_cast<float4*>(&sw[k0 + 3][h0]);
        FMA4(a0, x0.x, w0); FMA4(a0, x0.y, w1); FMA4(a0, x0.z, w2); FMA4(a0, x0.w, w3);
        FMA4(a1, x1.x, w0); FMA4(a1, x1.y, w1); FMA4(a1, x1.z, w2); FMA4(a1, x1.w, w3);
        FMA4(a2, x2.x, w0); FMA4(a2, x2.y, w1); FMA4(a2, x2.z, w2); FMA4(a2, x2.w, w3);
        FMA4(a3, x3.x, w0); FMA4(a3, x3.y, w1); FMA4(a3, x3.z, w2); FMA4(a3, x3.w, w3);
    }
    int n = n0 + nb;
    if (n + 0 < N) *reinterpret_cast<float4*>(Y + (size_t)(n + 0) * 64 + h0) = a0;
    if (n + 1 < N) *reinterpret_cast<float4*>(Y + (size_t)(n + 1) * 64 + h0) = a1;
    if (n + 2 < N) *reinterpret_cast<float4*>(Y + (size_t)(n + 2) * 64 + h0) = a2;
    if (n + 3 < N) *reinterpret_cast<float4*>(Y + (size_t)(n + 3) * 64 + h0) = a3;
}

// T[n,c] = relu(H[n,:64]+b1) @ W2[:,c], c < 40 (h padded to 64 with zero cols).
__global__ __launch_bounds__(256) void k_gemm2(const float* __restrict__ H,
                                               const float* __restrict__ b1,
                                               const float* __restrict__ W2,
                                               float* __restrict__ T, int N) {
    __shared__ float sh[64][68];
    __shared__ float sw[64][68];
    const int tid = threadIdx.x;
    const int n0 = blockIdx.x * 64;
    const bool full = (n0 + 64 <= N);
    // stage W2 (64x40 -> 64x64 zero-padded)
#pragma unroll
    for (int j = 0; j < 4; ++j) {
        int idx = (tid + j * 256) * 4;
        int k = idx >> 6, h = idx & 63;
        float4 v = make_float4(0.f, 0.f, 0.f, 0.f);
        if (h < 40) v = *reinterpret_cast<const float4*>(W2 + k * 40 + h);
        *reinterpret_cast<float4*>(&sw[k][h]) = v;
    }
    // stage relu(H + b1) tile (64x64)
#pragma unroll
    for (int j = 0; j < 4; ++j) {
        int idx = (tid + j * 256) * 4;
        int n = idx >> 6, k = idx & 63;
        float4 v = make_float4(0.f, 0.f, 0.f, 0.f);
        if (full || n0 + n < N) {
            float4 hv = *reinterpret_cast<const float4*>(H + (size_t)(n0 + n) * 64 + k);
            float4 bv = *reinterpret_cast<const float4*>(b1 + k);
            v.x = fmaxf(hv.x + bv.x, 0.f); v.y = fmaxf(hv.y + bv.y, 0.f);
            v.z = fmaxf(hv.z + bv.z, 0.f); v.w = fmaxf(hv.w + bv.w, 0.f);
        }
        *reinterpret_cast<float4*>(&sh[n][k]) = v;
    }
    __syncthreads();
    const int lane = tid & 63, wid = tid >> 6;
    const int h0 = (lane & 15) * 4;
    const int nb = wid * 16 + (lane >> 4) * 4;
    float4 a0 = {0,0,0,0}, a1 = {0,0,0,0}, a2 = {0,0,0,0}, a3 = {0,0,0,0};
#pragma unroll 4
    for (int k0 = 0; k0 < 64; k0 += 4) {
        float4 x0 = *reinterpret_cast<float4*>(&sh[nb + 0][k0]);
        float4 x1 = *reinterpret_cast<float4*>(&sh[nb + 1][k0]);
        float4 x2 = *reinterpret_cast<float4*>(&sh[nb + 2][k0]);
        float4 x3 = *reinterpret_cast<float4*>(&sh[nb + 3][k0]);
        float4 w0 = *reinterpret_cast<float4*>(&sw[k0 + 0][h0]);
        float4 w1 = *reinterpret_cast<float4*>(&sw[k0 + 1][h0]);
        float4 w2 = *reinterpret_cast<float4*>(&sw[k0 + 2][h0]);
        float4 w3 = *reinterpret_cast<float4*>(&sw[k0 + 3][h0]);
        FMA4(a0, x0.x, w0); FMA4(a0, x0.y, w1); FMA4(a0, x0.z, w2); FMA4(a0, x0.w, w3);
        FMA4(a1, x1.x, w0); FMA4(a1, x1.y, w1); FMA4(a1, x1.z, w2); FMA4(a1, x1.w, w3);
        FMA4(a2, x2.x, w0); FMA4(a2, x2.y, w1); FMA4(a2, x2.z, w2); FMA4(a2, x2.w, w3);
        FMA4(a3, x3.x, w0); FMA4(a3, x3.y, w1); FMA4(a3, x3.z, w2); FMA4(a3, x3.w, w3);
    }
    if (h0 < 40) {
        int n = n0 + nb;
        if (n + 0 < N) *reinterpret_cast<float4*>(T + (size_t)(n + 0) * 40 + h0) = a0;
        if (n + 1 < N) *reinterpret_cast<float4*>(T + (size_t)(n + 1) * 40 + h0) = a1;
        if (n + 2 < N) *reinterpret_cast<float4*>(T + (size_t)(n + 2) * 40 + h0) = a2;
        if (n + 3 < N) *reinterpret_cast<float4*>(T + (size_t)(n + 3) * 40 + h0) = a3;
    }
}

// out[n,c] = log_softmax(T[n,:40] + b2)   one wave per node, lanes >= 40 padded
__global__ void k_bias_lsm(const float* __restrict__ T, const float* __restrict__ b2,
                           float* __restrict__ Y, int N) {
    int gid = blockIdx.x * blockDim.x + threadIdx.x;
    int node = gid >> 6;
    int lane = threadIdx.x & 63;
    if (node >= N) return;
    float v = (lane < 40) ? T[(size_t)node * 40 + lane] + b2[lane] : -INFINITY;
    float m = v;
    for (int off = 32; off >= 1; off >>= 1) m = fmaxf(m, __shfl_xor(m, off));
    float ev = (lane < 40) ? expf(v - m) : 0.0f;
    float s = ev;
    for (int off = 32; off >= 1; off >>= 1) s += __shfl_xor(s, off);
    if (lane < 40) Y[(size_t)node * 40 + lane] = v - m - logf(s);
}

// ---------------- launch ----------------

extern "C" void kernel_launch(void* const* d_in, const int* in_sizes, int n_in,
                              void* d_out, int out_size, void* d_ws, size_t ws_size,
                              hipStream_t stream) {
    const float* x  = (const float*)d_in[0];
    const int*   ei = (const int*)d_in[1];
    const float* W1 = (const float*)d_in[2];
    const float* b1 = (const float*)d_in[3];
    const float* W2 = (const float*)d_in[4];
    const float* b2 = (const float*)d_in[5];
    float* out = (float*)d_out;

    const int H = in_sizes[3];            // 64
    const int F = in_sizes[2] / H;        // 128
    const int N = in_sizes[0] / F;        // 100000
    const int E = in_sizes[1] / 2;        // 1600000
    (void)ws_size; (void)n_in; (void)out_size;

    const int* src = ei;
    const int* dst = ei + E;
    const int NB = div_up(N, BKT);        // buckets
    const int NSB = div_up(N, SCH);       // scan blocks (49)

    // workspace layout (4-byte elems)
    const int Npad = (N + 256) & ~255;          // covers N+1
    float* dis  = (float*)d_ws;                 // N
    int*   cnt  = (int*)(dis + Npad);           // N
    int*   rp   = cnt + Npad;                   // N+1
    int*   cur  = rp + Npad;                    // N
    int*   bcur = cur + Npad;                   // NB
    int*   bsum = bcur + ((NB + 255) & ~255);   // NSB
    int*   csrc = bsum + ((NSB + 255) & ~255);  // E
    float* bufA = (float*)(csrc + ((E + 255) & ~255));   // N*64
    float* bufB = bufA + (size_t)N * 64;                 // N*64
    uint2* pairs = (uint2*)bufB;                // 2E ints, aliases bufB (dead until prop 1)

    const int B = 256;

    // ---- CSR build ----
    k_zero_i32<<<div_up(N, B), B, 0, stream>>>(cnt, N);
    k_cnt<<<div_up(E, B * 8), B, 0, stream>>>(dst, cnt, E);
    k_scan_part<<<NSB, 256, 0, stream>>>(cnt, bsum, N);
    k_scan_bsums<<<1, 1024, 0, stream>>>(bsum, rp + N, NSB);
    k_scan_apply<<<NSB, 256, 0, stream>>>(cnt, bsum, rp, cur, dis, N);
    k_binit<<<div_up(NB, B), B, 0, stream>>>(rp, bcur, NB);
    k_bucket<<<div_up(E, B), B, 0, stream>>>(src, dst, bcur, pairs, E);
    k_place<<<div_up(E, B), B, 0, stream>>>(pairs, cur, csrc, E);

    // ---- layer 1 (commuted): Y0 = X @ W1, then 2 props at F=64 ----
    k_gemm1<<<div_up(N, 64), 256, 0, stream>>>(x, W1, bufA, N);
    k_prop_gather<64><<<div_up((long long)N * 16, B), B, 0, stream>>>(rp, csrc, dis, bufA, bufB, N);
    k_prop_gather<64><<<div_up((long long)N * 16, B), B, 0, stream>>>(rp, csrc, dis, bufB, bufA, N);

    // ---- layer 2 (commuted): T = relu(h + b1) @ W2, then 2 props at F=40 ----
    k_gemm2<<<div_up(N, 64), 256, 0, stream>>>(bufA, b1, W2, bufB, N);
    k_prop_gather<40><<<div_up((long long)N * 10, B), B, 0, stream>>>(rp, csrc, dis, bufB, bufA, N);
    k_prop_gather<40><<<div_up((long long)N * 10, B), B, 0, stream>>>(rp, csrc, dis, bufA, bufB, N);

    // ---- epilogue: out = log_softmax(T + b2) ----
    k_bias_lsm<<<div_up((long long)N * 64, 256), 256, 0, stream>>>(bufB, b2, out, N);
}

// Round 8
// 456.857 us; speedup vs baseline: 1.7148x; 1.1107x over previous
//
#include <hip/hip_runtime.h>
#include <math.h>

__host__ __device__ static inline int div_up(long long a, long long b) { return (int)((a + b - 1) / b); }

#define SCH 2048              // scan chunk per block
#define NXCD 8                // XCD slices for false-sharing-free placement
#define PM 128                // edge chunks for k_place_direct (grid = 8*PM)

// ---------------- CSR build ----------------

__global__ void k_zero_i32(int* __restrict__ p, int n) {
    int i = blockIdx.x * blockDim.x + threadIdx.x;
    if (i < n) p[i] = 0;
}

__global__ void k_cnt(const int* __restrict__ dst, int* __restrict__ cnt, int E) {
    int i = blockIdx.x * blockDim.x + threadIdx.x;
    int stride = gridDim.x * blockDim.x;
    for (; i < E; i += stride) atomicAdd(&cnt[dst[i]], 1);
}

// Phase 1: per-block sums of SCH-element chunks.
__global__ void k_scan_part(const int* __restrict__ cnt, int* __restrict__ bsum, int N) {
    __shared__ int ws[4];
    int base = blockIdx.x * SCH + threadIdx.x * 8;
    int t = 0;
#pragma unroll
    for (int j = 0; j < 8; ++j) {
        int idx = base + j;
        if (idx < N) t += cnt[idx];
    }
    for (int off = 32; off >= 1; off >>= 1) t += __shfl_xor(t, off);
    int lane = threadIdx.x & 63, wid = threadIdx.x >> 6;
    if (lane == 0) ws[wid] = t;
    __syncthreads();
    if (threadIdx.x == 0) bsum[blockIdx.x] = ws[0] + ws[1] + ws[2] + ws[3];
}

// Phase 2: exclusive scan of block sums (NB <= 1024) + grand total -> rpN.
__global__ void k_scan_bsums(int* __restrict__ bsum, int* __restrict__ rpN, int NB) {
    __shared__ int wsum[16];
    int tid = threadIdx.x;
    int v = (tid < NB) ? bsum[tid] : 0;
    int lane = tid & 63, wid = tid >> 6;
    int x = v;
    for (int off = 1; off < 64; off <<= 1) {
        int y = __shfl_up(x, off);
        if (lane >= off) x += y;
    }
    if (lane == 63) wsum[wid] = x;
    __syncthreads();
    if (tid < 16) {
        int s = wsum[tid];
        for (int off = 1; off < 16; off <<= 1) {
            int y = __shfl_up(s, off);
            if (tid >= off) s += y;
        }
        wsum[tid] = s;
    }
    __syncthreads();
    int woff = (wid > 0) ? wsum[wid - 1] : 0;
    int excl = woff + x - v;
    if (tid < NB) bsum[tid] = excl;
    if (tid == NB - 1) rpN[0] = excl + v;
}

// Phase 3: local exclusive scan + block offset; emits rp, cur, dis.
__global__ void k_scan_apply(const int* __restrict__ cnt, const int* __restrict__ bsum,
                             int* __restrict__ rp, int* __restrict__ cur,
                             float* __restrict__ dis, int N) {
    __shared__ int wsum[4];
    int tid = threadIdx.x;
    int base = blockIdx.x * SCH + tid * 8;
    int v[8];
    int t = 0;
#pragma unroll
    for (int j = 0; j < 8; ++j) {
        int idx = base + j;
        v[j] = (idx < N) ? cnt[idx] : 0;
        t += v[j];
    }
    int lane = tid & 63, wid = tid >> 6;
    int x = t;
    for (int off = 1; off < 64; off <<= 1) {
        int y = __shfl_up(x, off);
        if (lane >= off) x += y;
    }
    if (lane == 63) wsum[wid] = x;
    __syncthreads();
    int woff = 0;
    for (int w = 0; w < wid; ++w) woff += wsum[w];
    int run = bsum[blockIdx.x] + woff + (x - t);
#pragma unroll
    for (int j = 0; j < 8; ++j) {
        int idx = base + j;
        if (idx < N) {
            rp[idx] = run;
            cur[idx] = run;
            dis[idx] = rsqrtf((float)v[j] + 1.0f);
        }
        run += v[j];
    }
}

// XCD-sliced direct CSR placement. Block b: slice = b % NXCD (node range),
// edge chunk = b / NXCD. Each csrc line is then written by blocks on a single
// XCD (round-robin dispatch), eliminating cross-XCD false sharing. Every edge
// is processed exactly once regardless of the physical mapping (perf-only).
__global__ __launch_bounds__(256) void k_place_direct(
        const int* __restrict__ src, const int* __restrict__ dst,
        int* __restrict__ cur, int* __restrict__ csrc, int E, int N) {
    const int slice = blockIdx.x % NXCD;
    const int chunk = blockIdx.x / NXCD;
    const int ns = div_up(N, NXCD);
    const int lo = slice * ns;
    const int hi = min(N, lo + ns);
    const int ce = div_up(E, PM) & ~3;            // chunk edges, multiple of 4
    const int e0 = chunk * ce;
    const int e1 = min(E, e0 + ce);
    // vectorized scan of [e0, e1)
    int i = e0 + threadIdx.x * 4;
    for (; i + 3 < e1; i += 256 * 4) {
        int4 d4 = *reinterpret_cast<const int4*>(dst + i);
        int4 s4 = *reinterpret_cast<const int4*>(src + i);
        if (d4.x >= lo && d4.x < hi) csrc[atomicAdd(&cur[d4.x], 1)] = s4.x;
        if (d4.y >= lo && d4.y < hi) csrc[atomicAdd(&cur[d4.y], 1)] = s4.y;
        if (d4.z >= lo && d4.z < hi) csrc[atomicAdd(&cur[d4.z], 1)] = s4.z;
        if (d4.w >= lo && d4.w < hi) csrc[atomicAdd(&cur[d4.w], 1)] = s4.w;
    }
    // tail (only the last chunk can be ragged)
    for (int j = i; j < e1; ++j) {
        int d = dst[j];
        if (d >= lo && d < hi) csrc[atomicAdd(&cur[d], 1)] = src[j];
    }
}

// ---------------- propagation: h_out = A_hat_norm @ h_in (gather form) ----------------

template<int F>
__global__ void k_prop_gather(const int* __restrict__ rp, const int* __restrict__ csrc,
                              const float* __restrict__ dis,
                              const float* __restrict__ hin, float* __restrict__ hout, int N) {
    constexpr int TPE = F / 4;
    int t = blockIdx.x * blockDim.x + threadIdx.x;
    int n = t / TPE;
    if (n >= N) return;
    int l = t % TPE;
    float dn = dis[n];
    float4 acc = *reinterpret_cast<const float4*>(hin + (size_t)n * F + 4 * l);
    float wn = dn * dn;
    acc.x *= wn; acc.y *= wn; acc.z *= wn; acc.w *= wn;
    int e = rp[n], end = rp[n + 1];
    for (; e + 3 < end; e += 4) {
        int s0 = csrc[e], s1 = csrc[e + 1], s2 = csrc[e + 2], s3 = csrc[e + 3];
        float w0 = dis[s0] * dn, w1 = dis[s1] * dn;
        float w2 = dis[s2] * dn, w3 = dis[s3] * dn;
        float4 v0 = *reinterpret_cast<const float4*>(hin + (size_t)s0 * F + 4 * l);
        float4 v1 = *reinterpret_cast<const float4*>(hin + (size_t)s1 * F + 4 * l);
        float4 v2 = *reinterpret_cast<const float4*>(hin + (size_t)s2 * F + 4 * l);
        float4 v3 = *reinterpret_cast<const float4*>(hin + (size_t)s3 * F + 4 * l);
        acc.x += w0 * v0.x + w1 * v1.x + w2 * v2.x + w3 * v3.x;
        acc.y += w0 * v0.y + w1 * v1.y + w2 * v2.y + w3 * v3.y;
        acc.z += w0 * v0.z + w1 * v1.z + w2 * v2.z + w3 * v3.z;
        acc.w += w0 * v0.w + w1 * v1.w + w2 * v2.w + w3 * v3.w;
    }
    for (; e < end; ++e) {
        int s0 = csrc[e];
        float w0 = dis[s0] * dn;
        float4 v0 = *reinterpret_cast<const float4*>(hin + (size_t)s0 * F + 4 * l);
        acc.x += w0 * v0.x; acc.y += w0 * v0.y; acc.z += w0 * v0.z; acc.w += w0 * v0.w;
    }
    *reinterpret_cast<float4*>(hout + (size_t)n * F + 4 * l) = acc;
}

// ---------------- dense layers (register-tiled) ----------------

#define FMA4(a, s, v) { (a).x += (s) * (v).x; (a).y += (s) * (v).y; \
                        (a).z += (s) * (v).z; (a).w += (s) * (v).w; }

// Y[n,h] = X[n,:128] @ W[:,h].  Tile: 64 nodes x 64 h, 4x4 per thread.
__global__ __launch_bounds__(256) void k_gemm1(const float* __restrict__ X,
                                               const float* __restrict__ W,
                                               float* __restrict__ Y, int N) {
    __shared__ float sx[64][132];
    __shared__ float sw[128][68];
    const int tid = threadIdx.x;
    const int n0 = blockIdx.x * 64;
    const bool full = (n0 + 64 <= N);
#pragma unroll
    for (int j = 0; j < 8; ++j) {
        int idx = (tid + j * 256) * 4;
        int k = idx >> 6, h = idx & 63;
        *reinterpret_cast<float4*>(&sw[k][h]) = *reinterpret_cast<const float4*>(W + idx);
    }
#pragma unroll
    for (int j = 0; j < 8; ++j) {
        int idx = (tid + j * 256) * 4;
        int n = idx >> 7, k = idx & 127;
        float4 v = make_float4(0.f, 0.f, 0.f, 0.f);
        if (full || n0 + n < N)
            v = *reinterpret_cast<const float4*>(X + (size_t)(n0 + n) * 128 + k);
        *reinterpret_cast<float4*>(&sx[n][k]) = v;
    }
    __syncthreads();
    const int lane = tid & 63, wid = tid >> 6;
    const int h0 = (lane & 15) * 4;
    const int nb = wid * 16 + (lane >> 4) * 4;
    float4 a0 = {0,0,0,0}, a1 = {0,0,0,0}, a2 = {0,0,0,0}, a3 = {0,0,0,0};
#pragma unroll 4
    for (int k0 = 0; k0 < 128; k0 += 4) {
        float4 x0 = *reinterpret_cast<float4*>(&sx[nb + 0][k0]);
        float4 x1 = *reinterpret_cast<float4*>(&sx[nb + 1][k0]);
        float4 x2 = *reinterpret_cast<float4*>(&sx[nb + 2][k0]);
        float4 x3 = *reinterpret_cast<float4*>(&sx[nb + 3][k0]);
        float4 w0 = *reinterpret_cast<float4*>(&sw[k0 + 0][h0]);
        float4 w1 = *reinterpret_cast<float4*>(&sw[k0 + 1][h0]);
        float4 w2 = *reinterpret_cast<float4*>(&sw[k0 + 2][h0]);
        float4 w3 = *reinterpret_cast<float4*>(&sw[k0 + 3][h0]);
        FMA4(a0, x0.x, w0); FMA4(a0, x0.y, w1); FMA4(a0, x0.z, w2); FMA4(a0, x0.w, w3);
        FMA4(a1, x1.x, w0); FMA4(a1, x1.y, w1); FMA4(a1, x1.z, w2); FMA4(a1, x1.w, w3);
        FMA4(a2, x2.x, w0); FMA4(a2, x2.y, w1); FMA4(a2, x2.z, w2); FMA4(a2, x2.w, w3);
        FMA4(a3, x3.x, w0); FMA4(a3, x3.y, w1); FMA4(a3, x3.z, w2); FMA4(a3, x3.w, w3);
    }
    int n = n0 + nb;
    if (n + 0 < N) *reinterpret_cast<float4*>(Y + (size_t)(n + 0) * 64 + h0) = a0;
    if (n + 1 < N) *reinterpret_cast<float4*>(Y + (size_t)(n + 1) * 64 + h0) = a1;
    if (n + 2 < N) *reinterpret_cast<float4*>(Y + (size_t)(n + 2) * 64 + h0) = a2;
    if (n + 3 < N) *reinterpret_cast<float4*>(Y + (size_t)(n + 3) * 64 + h0) = a3;
}

// T[n,c] = relu(H[n,:64]+b1) @ W2[:,c], c < 40 (padded to 64 zero cols).
__global__ __launch_bounds__(256) void k_gemm2(const float* __restrict__ H,
                                               const float* __restrict__ b1,
                                               const float* __restrict__ W2,
                                               float* __restrict__ T, int N) {
    __shared__ float sh[64][68];
    __shared__ float sw[64][68];
    const int tid = threadIdx.x;
    const int n0 = blockIdx.x * 64;
    const bool full = (n0 + 64 <= N);
#pragma unroll
    for (int j = 0; j < 4; ++j) {
        int idx = (tid + j * 256) * 4;
        int k = idx >> 6, h = idx & 63;
        float4 v = make_float4(0.f, 0.f, 0.f, 0.f);
        if (h < 40) v = *reinterpret_cast<const float4*>(W2 + k * 40 + h);
        *reinterpret_cast<float4*>(&sw[k][h]) = v;
    }
#pragma unroll
    for (int j = 0; j < 4; ++j) {
        int idx = (tid + j * 256) * 4;
        int n = idx >> 6, k = idx & 63;
        float4 v = make_float4(0.f, 0.f, 0.f, 0.f);
        if (full || n0 + n < N) {
            float4 hv = *reinterpret_cast<const float4*>(H + (size_t)(n0 + n) * 64 + k);
            float4 bv = *reinterpret_cast<const float4*>(b1 + k);
            v.x = fmaxf(hv.x + bv.x, 0.f); v.y = fmaxf(hv.y + bv.y, 0.f);
            v.z = fmaxf(hv.z + bv.z, 0.f); v.w = fmaxf(hv.w + bv.w, 0.f);
        }
        *reinterpret_cast<float4*>(&sh[n][k]) = v;
    }
    __syncthreads();
    const int lane = tid & 63, wid = tid >> 6;
    const int h0 = (lane & 15) * 4;
    const int nb = wid * 16 + (lane >> 4) * 4;
    float4 a0 = {0,0,0,0}, a1 = {0,0,0,0}, a2 = {0,0,0,0}, a3 = {0,0,0,0};
#pragma unroll 4
    for (int k0 = 0; k0 < 64; k0 += 4) {
        float4 x0 = *reinterpret_cast<float4*>(&sh[nb + 0][k0]);
        float4 x1 = *reinterpret_cast<float4*>(&sh[nb + 1][k0]);
        float4 x2 = *reinterpret_cast<float4*>(&sh[nb + 2][k0]);
        float4 x3 = *reinterpret_cast<float4*>(&sh[nb + 3][k0]);
        float4 w0 = *reinterpret_cast<float4*>(&sw[k0 + 0][h0]);
        float4 w1 = *reinterpret_cast<float4*>(&sw[k0 + 1][h0]);
        float4 w2 = *reinterpret_cast<float4*>(&sw[k0 + 2][h0]);
        float4 w3 = *reinterpret_cast<float4*>(&sw[k0 + 3][h0]);
        FMA4(a0, x0.x, w0); FMA4(a0, x0.y, w1); FMA4(a0, x0.z, w2); FMA4(a0, x0.w, w3);
        FMA4(a1, x1.x, w0); FMA4(a1, x1.y, w1); FMA4(a1, x1.z, w2); FMA4(a1, x1.w, w3);
        FMA4(a2, x2.x, w0); FMA4(a2, x2.y, w1); FMA4(a2, x2.z, w2); FMA4(a2, x2.w, w3);
        FMA4(a3, x3.x, w0); FMA4(a3, x3.y, w1); FMA4(a3, x3.z, w2); FMA4(a3, x3.w, w3);
    }
    if (h0 < 40) {
        int n = n0 + nb;
        if (n + 0 < N) *reinterpret_cast<float4*>(T + (size_t)(n + 0) * 40 + h0) = a0;
        if (n + 1 < N) *reinterpret_cast<float4*>(T + (size_t)(n + 1) * 40 + h0) = a1;
        if (n + 2 < N) *reinterpret_cast<float4*>(T + (size_t)(n + 2) * 40 + h0) = a2;
        if (n + 3 < N) *reinterpret_cast<float4*>(T + (size_t)(n + 3) * 40 + h0) = a3;
    }
}

// out[n,c] = log_softmax(T[n,:40] + b2)   one wave per node, lanes >= 40 padded
__global__ void k_bias_lsm(const float* __restrict__ T, const float* __restrict__ b2,
                           float* __restrict__ Y, int N) {
    int gid = blockIdx.x * blockDim.x + threadIdx.x;
    int node = gid >> 6;
    int lane = threadIdx.x & 63;
    if (node >= N) return;
    float v = (lane < 40) ? T[(size_t)node * 40 + lane] + b2[lane] : -INFINITY;
    float m = v;
    for (int off = 32; off >= 1; off >>= 1) m = fmaxf(m, __shfl_xor(m, off));
    float ev = (lane < 40) ? expf(v - m) : 0.0f;
    float s = ev;
    for (int off = 32; off >= 1; off >>= 1) s += __shfl_xor(s, off);
    if (lane < 40) Y[(size_t)node * 40 + lane] = v - m - logf(s);
}

// ---------------- launch ----------------

extern "C" void kernel_launch(void* const* d_in, const int* in_sizes, int n_in,
                              void* d_out, int out_size, void* d_ws, size_t ws_size,
                              hipStream_t stream) {
    const float* x  = (const float*)d_in[0];
    const int*   ei = (const int*)d_in[1];
    const float* W1 = (const float*)d_in[2];
    const float* b1 = (const float*)d_in[3];
    const float* W2 = (const float*)d_in[4];
    const float* b2 = (const float*)d_in[5];
    float* out = (float*)d_out;

    const int H = in_sizes[3];            // 64
    const int F = in_sizes[2] / H;        // 128
    const int N = in_sizes[0] / F;        // 100000
    const int E = in_sizes[1] / 2;        // 1600000
    (void)ws_size; (void)n_in; (void)out_size;

    const int* src = ei;
    const int* dst = ei + E;
    const int NSB = div_up(N, SCH);       // scan blocks (49)

    // workspace layout (4-byte elems)
    const int Npad = (N + 256) & ~255;          // covers N+1
    float* dis  = (float*)d_ws;                 // N
    int*   cnt  = (int*)(dis + Npad);           // N
    int*   rp   = cnt + Npad;                   // N+1
    int*   cur  = rp + Npad;                    // N
    int*   bsum = cur + Npad;                   // NSB
    int*   csrc = bsum + ((NSB + 255) & ~255);  // E
    float* bufA = (float*)(csrc + ((E + 255) & ~255));   // N*64
    float* bufB = bufA + (size_t)N * 64;                 // N*64

    const int B = 256;

    // ---- CSR build ----
    k_zero_i32<<<div_up(N, B), B, 0, stream>>>(cnt, N);
    k_cnt<<<div_up(E, B * 8), B, 0, stream>>>(dst, cnt, E);
    k_scan_part<<<NSB, 256, 0, stream>>>(cnt, bsum, N);
    k_scan_bsums<<<1, 1024, 0, stream>>>(bsum, rp + N, NSB);
    k_scan_apply<<<NSB, 256, 0, stream>>>(cnt, bsum, rp, cur, dis, N);
    k_place_direct<<<NXCD * PM, 256, 0, stream>>>(src, dst, cur, csrc, E, N);

    // ---- layer 1 (commuted): Y0 = X @ W1, then 2 props at F=64 ----
    k_gemm1<<<div_up(N, 64), 256, 0, stream>>>(x, W1, bufA, N);
    k_prop_gather<64><<<div_up((long long)N * 16, B), B, 0, stream>>>(rp, csrc, dis, bufA, bufB, N);
    k_prop_gather<64><<<div_up((long long)N * 16, B), B, 0, stream>>>(rp, csrc, dis, bufB, bufA, N);

    // ---- layer 2 (commuted): T = relu(h + b1) @ W2, then 2 props at F=40 ----
    k_gemm2<<<div_up(N, 64), 256, 0, stream>>>(bufA, b1, W2, bufB, N);
    k_prop_gather<40><<<div_up((long long)N * 10, B), B, 0, stream>>>(rp, csrc, dis, bufB, bufA, N);
    k_prop_gather<40><<<div_up((long long)N * 10, B), B, 0, stream>>>(rp, csrc, dis, bufA, bufB, N);

    // ---- epilogue: out = log_softmax(T + b2) ----
    k_bias_lsm<<<div_up((long long)N * 64, 256), 256, 0, stream>>>(bufB, b2, out, N);
}